// Round 7
// baseline (92.462 us; speedup 1.0000x reference)
//
#include <hip/hip_runtime.h>
#include <math.h>

// GMM score, rescaled: out_j = (E_w[td] - x_j) / sigma2_j
// w_i = exp(-0.5 (td_i - x_j)^2 / sigma2_j), sigma2_j = (exp(2 t_j ln25)-1)/(2 ln25)
//
// Model (R1-R6): dur = ~41us harness ws-poison fill (fixed) + kernel + gap.
// Kernel floor: 1 v_exp_f32 (~20cyc, issue-serial; throughput-bound per R2's
// JPT-invariance) + 4 pk ops per 2 evals = 47.8 cyc/128-eval bundle -> ~41us.
// R3 sw-exp2 REGRESSION (73us). R4 fence-fusion REGRESSION (140us).
// R5 fused+global-load: 49.6 (latency stall). R6 fused+LDS chunks: 43.7us,
// total 92.4 (best). Residual vs floor = 2.7us staging overhead: 16 barriers
// (2 per chunk x 8 chunks) + drains.
// R7 (this round): ping-pong LDS dbuf (ONE barrier per chunk; prev iter's
// barrier already protects the buffer being overwritten) + CH 2048->4096
// (NC 8->4). Barriers 16 -> 4. Loads for c+1 issue BEFORE compute (T14),
// ds_write after, barrier last. Prediction: kernel 41.5-42.5us, LDS ~34KB,
// total ~90-91us. Stop trigger: kernel >=43.5 -> R6 was the floor, declare
// roofline (fill 41 + kernel 41 + gap ~5-8 fully accounts the total).

typedef float v2f __attribute__((ext_vector_type(2)));

#define BLK   256
#define JB    16     // j's per block
#define PARTS 16     // N-part groups per block (BLK/JB)
#define CH    4096   // td elements per LDS chunk (16 KB); x2 ping-pong

#if __has_builtin(__builtin_amdgcn_exp2f)
#define EXP2(x) __builtin_amdgcn_exp2f(x)
#else
#define EXP2(x) exp2f(x)
#endif

__device__ __forceinline__ float sigma2_of(float tj) {
  const float TWO_LOG_S = 6.4377516497364011f;   // 2*ln(25)
  return (__expf(TWO_LOG_S * tj) - 1.0f) / TWO_LOG_S;
}

__device__ __forceinline__ float4 load_pad(const float* __restrict__ td,
                                           int gi, int N) {
  // pad -> d^2 = inf -> exp2(-inf) = 0 (weightless)
  if (gi + 3 < N) return *(const float4*)(td + gi);
  float4 v;
  v.x = (gi + 0 < N) ? td[gi + 0] : 1e30f;
  v.y = (gi + 1 < N) ? td[gi + 1] : 1e30f;
  v.z = (gi + 2 < N) ? td[gi + 2] : 1e30f;
  v.w = (gi + 3 < N) ? td[gi + 3] : 1e30f;
  return v;
}

__launch_bounds__(BLK, 4)
__global__ void gmm_fused(const float* __restrict__ x,
                          const float* __restrict__ t,
                          const float* __restrict__ td,
                          float* __restrict__ out,
                          int N, int B) {
  __shared__ float lds[2][CH];          // ping-pong chunk buffers (32 KB)
  __shared__ float nbuf[PARTS * JB];
  __shared__ float dbuf[PARTS * JB];

  const int tid  = threadIdx.x;
  const int jl   = tid & (JB - 1);      // j-lane within block
  const int part = tid >> 4;            // N-part group (0..15)
  const int j    = blockIdx.x * JB + jl;

  float r = 0.0f, y = 0.0f;
  if (j < B) {
    const float HALF_LOG2E = 0.72134752044448170f;  // 0.5 * log2(e)
    float s2 = sigma2_of(t[j]);
    r = __fsqrt_rn(HALF_LOG2E / s2);   // d = (td - x)*r ; arg = -d^2 (base-2)
    y = x[j] * r;
  }

  const v2f rv  = {r, r};
  const v2f nyv = {-y, -y};

  // accumulators persist across chunks: 4 num + 4 den (v2f)
  v2f n0 = {0.f, 0.f}, n1 = {0.f, 0.f}, n2 = {0.f, 0.f}, n3 = {0.f, 0.f};
  v2f d0 = {0.f, 0.f}, d1 = {0.f, 0.f}, d2 = {0.f, 0.f}, d3 = {0.f, 0.f};

#define GROUP(v, nacc, dacc)                                            \
  {                                                                     \
    v2f dd = __builtin_elementwise_fma(v, rv, nyv);                     \
    v2f qq = dd * dd;                                                   \
    v2f pp;                                                             \
    pp.x = EXP2(-qq.x); pp.y = EXP2(-qq.y);                             \
    dacc += pp;                                                         \
    nacc = __builtin_elementwise_fma(pp, v, nacc);                      \
  }

  const int NC = (N + CH - 1) / CH;     // 4 chunks for N=16384

  // stage chunk 0 into buffer 0 (4 coalesced float4 slots per thread)
  {
    float4 s0 = load_pad(td, (tid          ) * 4, N);
    float4 s1 = load_pad(td, (tid +     BLK) * 4, N);
    float4 s2 = load_pad(td, (tid + 2 * BLK) * 4, N);
    float4 s3 = load_pad(td, (tid + 3 * BLK) * 4, N);
    float4* dst = (float4*)lds[0];
    dst[tid]           = s0;
    dst[tid +     BLK] = s1;
    dst[tid + 2 * BLK] = s2;
    dst[tid + 3 * BLK] = s3;
  }
  __syncthreads();

  for (int c = 0; c < NC; ++c) {
    // T14 issue-early: next chunk's global loads go out before compute,
    // their vmcnt wait lands at the ds_write below (after compute).
    float4 s0 = {0,0,0,0}, s1 = {0,0,0,0}, s2 = {0,0,0,0}, s3 = {0,0,0,0};
    const bool more = (c + 1 < NC);
    if (more) {
      const int nb = (c + 1) * CH;
      s0 = load_pad(td, nb + (tid          ) * 4, N);
      s1 = load_pad(td, nb + (tid +     BLK) * 4, N);
      s2 = load_pad(td, nb + (tid + 2 * BLK) * 4, N);
      s3 = load_pad(td, nb + (tid + 3 * BLK) * 4, N);
    }

    // compute current chunk from buf[c&1]
    const float4* l4 = (const float4*)lds[c & 1];
    #pragma unroll 4
    for (int k = 0; k < CH / 64; k += 2) {
      float4 v0 = l4[part + 16 * k];        // 4 distinct addrs/wave, 16-way
      float4 v1 = l4[part + 16 * k + 16];   //   broadcast, banks 0-15: clean
      v2f va = {v0.x, v0.y}, vb = {v0.z, v0.w};
      v2f vc = {v1.x, v1.y}, vd = {v1.z, v1.w};
      GROUP(va, n0, d0)
      GROUP(vb, n1, d1)
      GROUP(vc, n2, d2)
      GROUP(vd, n3, d3)
    }

    if (more) {
      // write next chunk into the idle buffer; prev iteration's barrier
      // guarantees every wave is done reading it. ONE barrier per chunk.
      float4* dst = (float4*)lds[(c + 1) & 1];
      dst[tid]           = s0;
      dst[tid +     BLK] = s1;
      dst[tid + 2 * BLK] = s2;
      dst[tid + 3 * BLK] = s3;
      __syncthreads();
    }
  }
#undef GROUP

  v2f numv = (n0 + n1) + (n2 + n3);
  v2f denv = (d0 + d1) + (d2 + d3);
  __syncthreads();   // all waves past last compute before reduce buffers fill
  nbuf[part * JB + jl] = numv.x + numv.y;
  dbuf[part * JB + jl] = denv.x + denv.y;
  __syncthreads();

  // Final combine: 16 threads, each sums 16 part-partials for its j.
  if (tid < JB && (blockIdx.x * JB + tid) < B) {
    const int jj = blockIdx.x * JB + tid;
    float num = 0.f, den = 0.f;
    #pragma unroll
    for (int p = 0; p < PARTS; ++p) {
      num += nbuf[p * JB + tid];   // lanes read consecutive floats: clean
      den += dbuf[p * JB + tid];
    }
    float sigma2 = sigma2_of(t[jj]);
    float evals = (den == 0.0f) ? 0.0f : (num / den);   // reference's guard
    out[jj] = (evals - x[jj]) / sigma2;
  }
}

extern "C" void kernel_launch(void* const* d_in, const int* in_sizes, int n_in,
                              void* d_out, int out_size, void* d_ws, size_t ws_size,
                              hipStream_t stream) {
  const float* x  = (const float*)d_in[0];
  const float* t  = (const float*)d_in[1];
  const float* td = (const float*)d_in[2];
  float* out = (float*)d_out;
  (void)d_ws; (void)ws_size;

  const int B = in_sizes[0];
  const int N = in_sizes[2];

  const int GX = (B + JB - 1) / JB;   // 1024 blocks for B=16384
  gmm_fused<<<GX, BLK, 0, stream>>>(x, t, td, out, N, B);
}